// Round 1
// 285.183 us; speedup vs baseline: 1.5013x; 1.5013x over previous
//
#include <hip/hip_runtime.h>
#include <hip/hip_cooperative_groups.h>
#include <stdint.h>

namespace cg = cooperative_groups;
typedef unsigned long long u64;

static constexpr int BB  = 16;
static constexpr int HH  = 720;
static constexpr int WW  = 1280;
static constexpr int HWP = HH * WW;                    // 921600
static constexpr int WORDS_X = WW / 64;                // 20
static constexpr long long OUT_ELEMS = (long long)BB * 3 * HWP;  // 44236800
static constexpr size_t OUT_BYTES = (size_t)OUT_ELEMS * 4;
static constexpr size_t PLANE_B = (size_t)BB * HH * WORDS_X * 8; // 1843200
static constexpr int N16 = (int)(OUT_ELEMS / 16);      // 2764800
// fallback coop output config
static constexpr int KGRID = 512;
static constexpr int KNT = KGRID * 256;
static constexpr int OSLOT = (N16 + KNT - 1) / KNT;    // 22

// ---------------------------------------------------------------------------
// Exact integer direction bin == floor((mod(atan2(gy,gx),pi)+pi/8)/(pi/4))%4.
// Boundary tests v <> u*(sqrt2 -+ 1) done as (v+-u)^2 <> 2u^2 (exact in int32;
// equality impossible: sqrt2 irrational). Validated against double version.
// ---------------------------------------------------------------------------
__device__ __forceinline__ int dirbin_i(int gx, int gy)
{
    if (gy == 0) return 0;
    int u = gx, v = gy;
    if (v < 0) { u = -u; v = -v; }
    if (u > 0) {
        int b2 = 2 * u * u;
        int a = v + u;
        if (a * a < b2) return 0;            // v < u*(sqrt2-1)
        int d = v - u;
        if (d < 0 || d * d < b2) return 1;   // v < u*(sqrt2+1)
        return 2;
    } else if (u == 0) {
        return 2;
    } else {
        int dw = -u;
        int b2 = 2 * dw * dw;
        int d = v - dw;
        if (d > 0 && d * d > b2) return 2;   // v > dw*(sqrt2+1)
        int a = v + dw;
        if (a * a > b2) return 3;            // v > dw*(sqrt2-1)
        return 0;
    }
}

// ---------------------------------------------------------------------------
// Kernel 1: fused quantize + Sobel + channel-argmax + NMS + double threshold
// -> strong/weak bitplanes [B][720][20] u64.  LDS in u32 (conflict-free).
// ---------------------------------------------------------------------------
__global__ __launch_bounds__(256)
void k_gradnms(const float* __restrict__ x, u64* __restrict__ splane,
               u64* __restrict__ wplane)
{
    __shared__ int qimg[3][20][72];    // quantized tile + 2 halo, 3 channels
    __shared__ int mtile[18][68];      // mag | bin<<12, tile + 1 halo

    const int blk = blockIdx.x;
    const int bx = blk % 20;
    const int t1 = blk / 20;
    const int by = t1 % 45;
    const int b  = t1 / 45;
    const int x0 = bx << 6, y0 = by << 4;
    const float* bp = x + (size_t)b * 3 * HWP;

    for (int i = threadIdx.x; i < 3 * 20 * 68; i += 256) {
        int seg = i / 68;              // 0..59  (c*20 + r)
        int col = i - seg * 68;
        int c   = seg / 20;
        int r   = seg - c * 20;
        int gy = y0 - 2 + r;   gy = gy < 0 ? 0 : (gy > HH - 1 ? HH - 1 : gy);
        int gx = x0 - 2 + col; gx = gx < 0 ? 0 : (gx > WW - 1 ? WW - 1 : gx);
        float v = bp[(size_t)c * HWP + gy * WW + gx];
        qimg[c][r][col] = (int)floorf(fminf(fmaxf(v, 0.0f), 1.0f) * 255.0f);
    }
    __syncthreads();

    for (int i = threadIdx.x; i < 18 * 66; i += 256) {
        int r = i / 66, cc = i - r * 66;
        int my = y0 - 1 + r, mx = x0 - 1 + cc;
        int pk = 0;
        if (my >= 0 && my < HH && mx >= 0 && mx < WW) {
            int bestm = -1, bgx = 0, bgy = 0;
#pragma unroll
            for (int ch = 0; ch < 3; ++ch) {
                int a00 = qimg[ch][r  ][cc], a01 = qimg[ch][r  ][cc+1], a02 = qimg[ch][r  ][cc+2];
                int a10 = qimg[ch][r+1][cc],                             a12 = qimg[ch][r+1][cc+2];
                int a20 = qimg[ch][r+2][cc], a21 = qimg[ch][r+2][cc+1], a22 = qimg[ch][r+2][cc+2];
                int gx = (a02 - a00) + 2 * (a12 - a10) + (a22 - a20);
                int gy = (a20 - a00) + 2 * (a21 - a01) + (a22 - a02);
                int m  = abs(gx) + abs(gy);
                if (m > bestm) { bestm = m; bgx = gx; bgy = gy; }  // first-max tie
            }
            pk = bestm | (dirbin_i(bgx, bgy) << 12);
        }
        mtile[r][cc] = pk;
    }
    __syncthreads();

    const int v = threadIdx.x >> 6, l = threadIdx.x & 63;
#pragma unroll
    for (int k = 0; k < 4; ++k) {
        int ry = v * 4 + k;
        int pk = mtile[ry + 1][l + 1];
        int m = pk & 0xFFF, bin = pk >> 12;
        int dy = (bin == 0) ? 0 : 1;
        int dx = (bin == 2) ? 0 : ((bin == 3) ? -1 : 1);
        int n1 = mtile[ry + 1 + dy][l + 1 + dx] & 0xFFF;
        int n2 = mtile[ry + 1 - dy][l + 1 - dx] & 0xFFF;
        int keep = (m >= n1) && (m >= n2);
        u64 sB = __ballot(keep && m >= 77);   // nms > 76.5
        u64 wB = __ballot(keep && m >= 26);   // nms > 25.5 (superset)
        if (l == 0) {
            size_t rb = ((size_t)b * HH + (y0 + ry)) * WORDS_X + bx;
            splane[rb] = sB;
            wplane[rb] = wB;
        }
    }
}

// ---------------------------------------------------------------------------
// Bit helpers
// ---------------------------------------------------------------------------
__device__ __forceinline__ u64 sh_up(u64 x, int k) {   // from lane-k (row above)
    int l = threadIdx.x & 63;
    u64 y = __shfl(x, l - k, 64);
    return (l >= k) ? y : 0ull;
}
__device__ __forceinline__ u64 sh_dn(u64 x, int k) {   // from lane+k (row below)
    int l = threadIdx.x & 63;
    u64 y = __shfl(x, l + k, 64);
    return (l + k < 64) ? y : 0ull;
}
__device__ __forceinline__ u64 dil(u64 x) { return x | (x << 1) | (x >> 1); }

__device__ __forceinline__ u64 hflood_L(u64 f, u64 w) {   // toward +x (higher bits)
    u64 p = w;
    f |= p & (f << 1);  p &= (p << 1);
    f |= p & (f << 2);  p &= (p << 2);
    f |= p & (f << 4);  p &= (p << 4);
    f |= p & (f << 8);  p &= (p << 8);
    f |= p & (f << 16); p &= (p << 16);
    f |= p & (f << 32);
    return f;
}
__device__ __forceinline__ u64 hflood_R(u64 f, u64 w) {   // toward -x
    u64 p = w;
    f |= p & (f >> 1);  p &= (p >> 1);
    f |= p & (f >> 2);  p &= (p >> 2);
    f |= p & (f >> 4);  p &= (p >> 4);
    f |= p & (f >> 8);  p &= (p >> 8);
    f |= p & (f >> 16); p &= (p >> 16);
    f |= p & (f >> 32);
    return f;
}
__device__ __forceinline__ u64 vflood(u64 f, u64 w) {     // KS over 64 lanes
    u64 p = w;
    f |= p & sh_up(f, 1);  p &= sh_up(p, 1);
    f |= p & sh_up(f, 2);  p &= sh_up(p, 2);
    f |= p & sh_up(f, 4);  p &= sh_up(p, 4);
    f |= p & sh_up(f, 8);  p &= sh_up(p, 8);
    f |= p & sh_up(f, 16); p &= sh_up(p, 16);
    f |= p & sh_up(f, 32);
    p = w;
    f |= p & sh_dn(f, 1);  p &= sh_dn(p, 1);
    f |= p & sh_dn(f, 2);  p &= sh_dn(p, 2);
    f |= p & sh_dn(f, 4);  p &= sh_dn(p, 4);
    f |= p & sh_dn(f, 8);  p &= sh_dn(p, 8);
    f |= p & sh_dn(f, 16); p &= sh_dn(p, 16);
    f |= p & sh_dn(f, 32);
    return f;
}

// ---------------------------------------------------------------------------
// Kernel 2 (plain, 16 blocks): whole-image hysteresis, all state in registers.
// lane = row (12 waves x 64 rows >= 720), 20 u64 words = full 1280-px row.
//
// v2 structure:
//   - inner(): wave-local 8-connected fixed point of one 64-row band
//     (h-closure + dil + vertical KS flood, repeated until stable; NO
//     barriers -> diagonal staircases converge inside ONE outer iteration
//     instead of 1 px per block-wide round).
//   - outer loop: pure seam exchange with frontier gating -- a wave whose
//     incoming seam seeds add no new bits does zero flood work.
// Fixed point identical to v1 (monotone flood; update order irrelevant).
// ---------------------------------------------------------------------------
__global__ __launch_bounds__(768)
void k_hyst_local(u64* __restrict__ splane, const u64* __restrict__ wplane)
{
    __shared__ u64 sTop[12][20], sBot[12][20];
    __shared__ int schg[2];

    const int b = blockIdx.x;
    const int r = threadIdx.x;
    const int l = threadIdx.x & 63;
    const int v = threadIdx.x >> 6;
    const bool valid = r < HH;
    const size_t base = ((size_t)b * HH + (valid ? r : 0)) * WORDS_X;

    u64 W[20], F[20];
#pragma unroll
    for (int j = 0; j < 20; ++j) {
        W[j] = valid ? wplane[base + j] : 0ull;
        F[j] = valid ? splane[base + j] : 0ull;
    }

    // wave-local full 8-connected closure of this 64-row band (no barriers)
    auto converge_band = [&]() {
        while (true) {
            // ---- horizontal exact closure: 2 sweeps with cross-word carry ----
            u64 carry = 0;
#pragma unroll
            for (int j = 0; j < 20; ++j) {
                u64 f = F[j] | (W[j] & carry);
                f = hflood_L(f, W[j]);
                F[j] = f;
                carry = (f >> 63) & 1ull;
            }
            carry = 0;
#pragma unroll
            for (int j = 19; j >= 0; --j) {
                u64 f = F[j] | (W[j] & (carry << 63));
                f = hflood_R(f, W[j]);
                F[j] = f;
                carry = f & 1ull;
            }
            // ---- vertical + diagonal inside the wave: dil seed + KS flood ----
            int ch = 0;
#pragma unroll
            for (int j = 0; j < 20; ++j) {
                u64 d = dil(F[j]);
                if (j > 0)  d |= (F[j-1] >> 63) & 1ull;
                if (j < 19) d |= (F[j+1] & 1ull) << 63;
                u64 up = sh_up(d, 1);
                u64 dn = sh_dn(d, 1);
                u64 f = F[j] | (W[j] & (up | dn));
                f = vflood(f, W[j]);
                ch |= (f != F[j]);
                F[j] = f;
            }
            // band fixed point: h-closed AND v-phase added nothing
            if (!__any(ch)) break;
        }
    };

    if (threadIdx.x == 0) { schg[0] = 0; schg[1] = 0; }
    converge_band();                       // initial local closure, all waves

    int iter = 0;
    while (true) {
        const int c = iter & 1;
        if (threadIdx.x == 0) schg[c ^ 1] = 0;   // reset other-parity flag

        // ---- publish seam rows (dilated, cross-word corners included) ----
        if (l == 0 || l == 63) {
#pragma unroll
            for (int j = 0; j < 20; ++j) {
                u64 d = dil(F[j]);
                if (j > 0)  d |= (F[j-1] >> 63) & 1ull;
                if (j < 19) d |= (F[j+1] & 1ull) << 63;
                if (l == 0) sTop[v][j] = d; else sBot[v][j] = d;
            }
        }
        __syncthreads();

        // ---- gather seam seeds; flood only if they add new bits ----
        int anynb = 0;
#pragma unroll
        for (int j = 0; j < 20; ++j) {
            u64 s = 0ull;
            if (l == 0  && v > 0)  s = sBot[v-1][j];
            else if (l == 63 && v < 11) s = sTop[v+1][j];
            u64 add = W[j] & s & ~F[j];
            anynb |= (add != 0ull);
            F[j] |= add;
        }
        if (__any(anynb)) {                 // wave-uniform (frontier gating)
            converge_band();
            schg[c] = 1;                    // benign multi-writer race
        }
        __syncthreads();
        if (!schg[c]) break;
        ++iter;
    }

#pragma unroll
    for (int j = 0; j < 20; ++j)
        if (valid) splane[base + j] = F[j];
}

// ---------------------------------------------------------------------------
// Kernel 3a (plain, fast path — planes in d_ws): expand bits -> float output
// ---------------------------------------------------------------------------
__global__ __launch_bounds__(256)
void k_out(const u64* __restrict__ splane, float* __restrict__ out)
{
    int i = blockIdx.x * 256 + threadIdx.x;    // 16-px output group, < N16
    int px  = i * 16;
    int bb  = px / (3 * HWP);
    int rem = px - bb * (3 * HWP);
    int yx  = rem % HWP;
    int y   = yx / WW;
    int xx  = yx - y * WW;
    u64 wv = splane[((size_t)bb * HH + y) * WORDS_X + (xx >> 6)];
    uint32_t bits = (uint32_t)((wv >> (xx & 63)) & 0xFFFFull);
    float4* o4 = (float4*)(out + (size_t)i * 16);
#pragma unroll
    for (int q = 0; q < 4; ++q) {
        float4 fv;
        fv.x = (bits >> (q * 4 + 0)) & 1 ? 1.0f : 0.0f;
        fv.y = (bits >> (q * 4 + 1)) & 1 ? 1.0f : 0.0f;
        fv.z = (bits >> (q * 4 + 2)) & 1 ? 1.0f : 0.0f;
        fv.w = (bits >> (q * 4 + 3)) & 1 ? 1.0f : 0.0f;
        o4[q] = fv;
    }
}

// ---------------------------------------------------------------------------
// Kernel 3b (coop fallback — planes in d_out tail): capture, sync, write
// ---------------------------------------------------------------------------
__global__ __launch_bounds__(256, 4)
void k_out_capture(const u64* __restrict__ splane, float* __restrict__ out)
{
    cg::grid_group grid = cg::this_grid();
    const int gtid = blockIdx.x * 256 + threadIdx.x;
    uint32_t vals[OSLOT];
#pragma unroll
    for (int n = 0; n < OSLOT; ++n) {
        int i = gtid + n * KNT;
        if (i < N16) {
            int px  = i * 16;
            int bb  = px / (3 * HWP);
            int rem = px - bb * (3 * HWP);
            int yx  = rem % HWP;
            int y   = yx / WW;
            int xx  = yx - y * WW;
            u64 wv = splane[((size_t)bb * HH + y) * WORDS_X + (xx >> 6)];
            vals[n] = (uint32_t)((wv >> (xx & 63)) & 0xFFFFull);
        }
    }
    grid.sync();
#pragma unroll
    for (int n = 0; n < OSLOT; ++n) {
        int i = gtid + n * KNT;
        if (i < N16) {
            uint32_t bits = vals[n];
            float4* o4 = (float4*)(out + (size_t)i * 16);
#pragma unroll
            for (int q = 0; q < 4; ++q) {
                float4 fv;
                fv.x = (bits >> (q * 4 + 0)) & 1 ? 1.0f : 0.0f;
                fv.y = (bits >> (q * 4 + 1)) & 1 ? 1.0f : 0.0f;
                fv.z = (bits >> (q * 4 + 2)) & 1 ? 1.0f : 0.0f;
                fv.w = (bits >> (q * 4 + 3)) & 1 ? 1.0f : 0.0f;
                o4[q] = fv;
            }
        }
    }
}

// ---------------------------------------------------------------------------
extern "C" void kernel_launch(void* const* d_in, const int* in_sizes, int n_in,
                              void* d_out, int out_size, void* d_ws, size_t ws_size,
                              hipStream_t stream)
{
    const float* x = (const float*)d_in[0];
    float* out = (float*)d_out;

    const bool use_ws = (d_ws != nullptr) && (ws_size >= 2 * PLANE_B);
    u64 *splane, *wplane;
    if (use_ws) {
        splane = (u64*)d_ws;
        wplane = (u64*)((char*)d_ws + PLANE_B);
    } else {
        char* tail = (char*)d_out + OUT_BYTES;
        wplane = (u64*)(tail - PLANE_B);
        splane = (u64*)(tail - 2 * PLANE_B);
    }

    k_gradnms<<<20 * 45 * BB, 256, 0, stream>>>(x, splane, wplane);
    k_hyst_local<<<BB, 768, 0, stream>>>(splane, wplane);

    if (use_ws) {
        k_out<<<N16 / 256, 256, 0, stream>>>(splane, out);
    } else {
        void* args[] = { (void*)&splane, (void*)&out };
        hipLaunchCooperativeKernel((void*)k_out_capture, dim3(KGRID), dim3(256),
                                   args, 0, stream);
    }
}

// Round 2
// 256.275 us; speedup vs baseline: 1.6707x; 1.1128x over previous
//
#include <hip/hip_runtime.h>
#include <hip/hip_cooperative_groups.h>
#include <stdint.h>

namespace cg = cooperative_groups;
typedef unsigned long long u64;

static constexpr int BB  = 16;
static constexpr int HH  = 720;
static constexpr int WW  = 1280;
static constexpr int HWP = HH * WW;                    // 921600
static constexpr int WORDS_X = WW / 64;                // 20
static constexpr long long OUT_ELEMS = (long long)BB * 3 * HWP;  // 44236800
static constexpr size_t OUT_BYTES = (size_t)OUT_ELEMS * 4;
static constexpr size_t PLANE_B = (size_t)BB * HH * WORDS_X * 8; // 1843200
static constexpr int N16 = (int)(OUT_ELEMS / 16);      // 2764800
// fallback coop output config
static constexpr int KGRID = 512;
static constexpr int KNT = KGRID * 256;
static constexpr int OSLOT = (N16 + KNT - 1) / KNT;    // 22

typedef short v4s __attribute__((ext_vector_type(4)));
union QW { u64 u; v4s v; };

// ---------------------------------------------------------------------------
// Exact integer direction bin == floor((mod(atan2(gy,gx),pi)+pi/8)/(pi/4))%4.
// Boundary tests v <> u*(sqrt2 -+ 1) done as (v+-u)^2 <> 2u^2 (exact in int32;
// equality impossible: sqrt2 irrational). Validated against double version.
// ---------------------------------------------------------------------------
__device__ __forceinline__ int dirbin_i(int gx, int gy)
{
    if (gy == 0) return 0;
    int u = gx, v = gy;
    if (v < 0) { u = -u; v = -v; }
    if (u > 0) {
        int b2 = 2 * u * u;
        int a = v + u;
        if (a * a < b2) return 0;            // v < u*(sqrt2-1)
        int d = v - u;
        if (d < 0 || d * d < b2) return 1;   // v < u*(sqrt2+1)
        return 2;
    } else if (u == 0) {
        return 2;
    } else {
        int dw = -u;
        int b2 = 2 * dw * dw;
        int d = v - dw;
        if (d > 0 && d * d > b2) return 2;   // v > dw*(sqrt2+1)
        int a = v + dw;
        if (a * a > b2) return 3;            // v > dw*(sqrt2-1)
        return 0;
    }
}

// ---------------------------------------------------------------------------
// Kernel 1 (v2): fused quantize + Sobel + channel-argmax + NMS + threshold.
// SWAR: 3 channels packed as 4xu16 in one u64 LDS word -> Sobel for all
// channels at once via short4 (v_pk_*_i16); 8x ds_read_b64 per pixel
// instead of 24x ds_read_b32.  All-integer, bit-identical semantics.
// ---------------------------------------------------------------------------
__global__ __launch_bounds__(256)
void k_gradnms(const float* __restrict__ x, u64* __restrict__ splane,
               u64* __restrict__ wplane)
{
    __shared__ u64 qimg[20][72];     // ch0|ch1|ch2|0 as u16x4; 11.25 KB
    __shared__ int mtile[18][68];    // mag | bin<<12, tile + 1 halo

    const int blk = blockIdx.x;
    const int bx = blk % 20;
    const int t1 = blk / 20;
    const int by = t1 % 45;
    const int b  = t1 / 45;
    const int x0 = bx << 6, y0 = by << 4;
    const float* bp = x + (size_t)b * 3 * HWP;

    for (int i = threadIdx.x; i < 20 * 68; i += 256) {
        int r   = i / 68;
        int col = i - r * 68;
        int gy = y0 - 2 + r;   gy = gy < 0 ? 0 : (gy > HH - 1 ? HH - 1 : gy);
        int gx = x0 - 2 + col; gx = gx < 0 ? 0 : (gx > WW - 1 ? WW - 1 : gx);
        const float* p = bp + (size_t)(gy * WW + gx);
        // trunc == floor for non-negative values
        int q0 = (int)(fminf(fmaxf(p[0],           0.0f), 1.0f) * 255.0f);
        int q1 = (int)(fminf(fmaxf(p[HWP],         0.0f), 1.0f) * 255.0f);
        int q2 = (int)(fminf(fmaxf(p[2 * HWP],     0.0f), 1.0f) * 255.0f);
        qimg[r][col] = (u64)(uint32_t)(q0 | (q1 << 16)) | ((u64)(uint32_t)q2 << 32);
    }
    __syncthreads();

    for (int i = threadIdx.x; i < 18 * 66; i += 256) {
        int r = i / 66, cc = i - r * 66;
        int my = y0 - 1 + r, mx = x0 - 1 + cc;
        int pk = 0;
        if (my >= 0 && my < HH && mx >= 0 && mx < WW) {
            QW w00, w01, w02, w10, w12, w20, w21, w22;
            w00.u = qimg[r    ][cc    ];
            w01.u = qimg[r    ][cc + 1];
            w02.u = qimg[r    ][cc + 2];
            w10.u = qimg[r + 1][cc    ];
            w12.u = qimg[r + 1][cc + 2];
            w20.u = qimg[r + 2][cc    ];
            w21.u = qimg[r + 2][cc + 1];
            w22.u = qimg[r + 2][cc + 2];
            v4s t1 = w02.v - w00.v, t2 = w12.v - w10.v, t3 = w22.v - w20.v;
            v4s gx4 = t1 + t2 + t2 + t3;                   // |gx| <= 1020
            v4s u1 = w20.v - w00.v, u2 = w21.v - w01.v, u3 = w22.v - w02.v;
            v4s gy4 = u1 + u2 + u2 + u3;                   // |gy| <= 1020
            v4s ax = __builtin_elementwise_max(gx4, -gx4);
            v4s ay = __builtin_elementwise_max(gy4, -gy4);
            QW mq; mq.v = ax + ay;                         // mag <= 2040
            int m0 = (int)(mq.u & 0xffffull);
            int m1 = (int)((mq.u >> 16) & 0xffffull);
            int m2 = (int)((mq.u >> 32) & 0xffffull);
            int bm = m0, bi = 0;                           // first-max tie
            if (m1 > bm) { bm = m1; bi = 1; }
            if (m2 > bm) { bm = m2; bi = 2; }
            QW gq; gq.v = gx4;
            QW hq; hq.v = gy4;
            int sh = bi << 4;
            int bgx = (int)(short)(gq.u >> sh);
            int bgy = (int)(short)(hq.u >> sh);
            pk = bm | (dirbin_i(bgx, bgy) << 12);
        }
        mtile[r][cc] = pk;
    }
    __syncthreads();

    const int v = threadIdx.x >> 6, l = threadIdx.x & 63;
#pragma unroll
    for (int k = 0; k < 4; ++k) {
        int ry = v * 4 + k;
        int pk = mtile[ry + 1][l + 1];
        int m = pk & 0xFFF, bin = pk >> 12;
        int dy = (bin == 0) ? 0 : 1;
        int dx = (bin == 2) ? 0 : ((bin == 3) ? -1 : 1);
        int n1 = mtile[ry + 1 + dy][l + 1 + dx] & 0xFFF;
        int n2 = mtile[ry + 1 - dy][l + 1 - dx] & 0xFFF;
        int keep = (m >= n1) && (m >= n2);
        u64 sB = __ballot(keep && m >= 77);   // nms > 76.5
        u64 wB = __ballot(keep && m >= 26);   // nms > 25.5 (superset)
        if (l == 0) {
            size_t rb = ((size_t)b * HH + (y0 + ry)) * WORDS_X + bx;
            splane[rb] = sB;
            wplane[rb] = wB;
        }
    }
}

// ---------------------------------------------------------------------------
// Bit helpers
// ---------------------------------------------------------------------------
__device__ __forceinline__ u64 sh_up(u64 x, int k) {   // from lane-k (row above)
    int l = threadIdx.x & 63;
    u64 y = __shfl(x, l - k, 64);
    return (l >= k) ? y : 0ull;
}
__device__ __forceinline__ u64 sh_dn(u64 x, int k) {   // from lane+k (row below)
    int l = threadIdx.x & 63;
    u64 y = __shfl(x, l + k, 64);
    return (l + k < 64) ? y : 0ull;
}
__device__ __forceinline__ u64 dil(u64 x) { return x | (x << 1) | (x >> 1); }

__device__ __forceinline__ u64 hflood_L(u64 f, u64 w) {   // toward +x (higher bits)
    u64 p = w;
    f |= p & (f << 1);  p &= (p << 1);
    f |= p & (f << 2);  p &= (p << 2);
    f |= p & (f << 4);  p &= (p << 4);
    f |= p & (f << 8);  p &= (p << 8);
    f |= p & (f << 16); p &= (p << 16);
    f |= p & (f << 32);
    return f;
}
__device__ __forceinline__ u64 hflood_R(u64 f, u64 w) {   // toward -x
    u64 p = w;
    f |= p & (f >> 1);  p &= (p >> 1);
    f |= p & (f >> 2);  p &= (p >> 2);
    f |= p & (f >> 4);  p &= (p >> 4);
    f |= p & (f >> 8);  p &= (p >> 8);
    f |= p & (f >> 16); p &= (p >> 16);
    f |= p & (f >> 32);
    return f;
}
__device__ __forceinline__ u64 vflood(u64 f, u64 w) {     // KS over 64 lanes
    u64 p = w;
    f |= p & sh_up(f, 1);  p &= sh_up(p, 1);
    f |= p & sh_up(f, 2);  p &= sh_up(p, 2);
    f |= p & sh_up(f, 4);  p &= sh_up(p, 4);
    f |= p & sh_up(f, 8);  p &= sh_up(p, 8);
    f |= p & sh_up(f, 16); p &= sh_up(p, 16);
    f |= p & sh_up(f, 32);
    p = w;
    f |= p & sh_dn(f, 1);  p &= sh_dn(p, 1);
    f |= p & sh_dn(f, 2);  p &= sh_dn(p, 2);
    f |= p & sh_dn(f, 4);  p &= sh_dn(p, 4);
    f |= p & sh_dn(f, 8);  p &= sh_dn(p, 8);
    f |= p & sh_dn(f, 16); p &= sh_dn(p, 16);
    f |= p & sh_dn(f, 32);
    return f;
}

// ---------------------------------------------------------------------------
// Kernel 2 (plain, 16 blocks): whole-image hysteresis, all state in registers.
// lane = row (12 waves x 64 rows >= 720), 20 u64 words = full 1280-px row.
// wave-local band fixed point + seam exchange with frontier gating.
// ---------------------------------------------------------------------------
__global__ __launch_bounds__(768)
void k_hyst_local(u64* __restrict__ splane, const u64* __restrict__ wplane)
{
    __shared__ u64 sTop[12][20], sBot[12][20];
    __shared__ int schg[2];

    const int b = blockIdx.x;
    const int r = threadIdx.x;
    const int l = threadIdx.x & 63;
    const int v = threadIdx.x >> 6;
    const bool valid = r < HH;
    const size_t base = ((size_t)b * HH + (valid ? r : 0)) * WORDS_X;

    u64 W[20], F[20];
#pragma unroll
    for (int j = 0; j < 20; ++j) {
        W[j] = valid ? wplane[base + j] : 0ull;
        F[j] = valid ? splane[base + j] : 0ull;
    }

    // wave-local full 8-connected closure of this 64-row band (no barriers)
    auto converge_band = [&]() {
        while (true) {
            // ---- horizontal exact closure: 2 sweeps with cross-word carry ----
            u64 carry = 0;
#pragma unroll
            for (int j = 0; j < 20; ++j) {
                u64 f = F[j] | (W[j] & carry);
                f = hflood_L(f, W[j]);
                F[j] = f;
                carry = (f >> 63) & 1ull;
            }
            carry = 0;
#pragma unroll
            for (int j = 19; j >= 0; --j) {
                u64 f = F[j] | (W[j] & (carry << 63));
                f = hflood_R(f, W[j]);
                F[j] = f;
                carry = f & 1ull;
            }
            // ---- vertical + diagonal inside the wave: dil seed + KS flood ----
            int ch = 0;
#pragma unroll
            for (int j = 0; j < 20; ++j) {
                u64 d = dil(F[j]);
                if (j > 0)  d |= (F[j-1] >> 63) & 1ull;
                if (j < 19) d |= (F[j+1] & 1ull) << 63;
                u64 up = sh_up(d, 1);
                u64 dn = sh_dn(d, 1);
                u64 f = F[j] | (W[j] & (up | dn));
                f = vflood(f, W[j]);
                ch |= (f != F[j]);
                F[j] = f;
            }
            // band fixed point: h-closed AND v-phase added nothing
            if (!__any(ch)) break;
        }
    };

    if (threadIdx.x == 0) { schg[0] = 0; schg[1] = 0; }
    converge_band();                       // initial local closure, all waves

    int iter = 0;
    while (true) {
        const int c = iter & 1;
        if (threadIdx.x == 0) schg[c ^ 1] = 0;   // reset other-parity flag

        // ---- publish seam rows (dilated, cross-word corners included) ----
        if (l == 0 || l == 63) {
#pragma unroll
            for (int j = 0; j < 20; ++j) {
                u64 d = dil(F[j]);
                if (j > 0)  d |= (F[j-1] >> 63) & 1ull;
                if (j < 19) d |= (F[j+1] & 1ull) << 63;
                if (l == 0) sTop[v][j] = d; else sBot[v][j] = d;
            }
        }
        __syncthreads();

        // ---- gather seam seeds; flood only if they add new bits ----
        int anynb = 0;
#pragma unroll
        for (int j = 0; j < 20; ++j) {
            u64 s = 0ull;
            if (l == 0  && v > 0)  s = sBot[v-1][j];
            else if (l == 63 && v < 11) s = sTop[v+1][j];
            u64 add = W[j] & s & ~F[j];
            anynb |= (add != 0ull);
            F[j] |= add;
        }
        if (__any(anynb)) {                 // wave-uniform (frontier gating)
            converge_band();
            schg[c] = 1;                    // benign multi-writer race
        }
        __syncthreads();
        if (!schg[c]) break;
        ++iter;
    }

#pragma unroll
    for (int j = 0; j < 20; ++j)
        if (valid) splane[base + j] = F[j];
}

// ---------------------------------------------------------------------------
// Kernel 3a (plain, fast path — planes in d_ws): expand bits -> float output
// ---------------------------------------------------------------------------
__global__ __launch_bounds__(256)
void k_out(const u64* __restrict__ splane, float* __restrict__ out)
{
    int i = blockIdx.x * 256 + threadIdx.x;    // 16-px output group, < N16
    int px  = i * 16;
    int bb  = px / (3 * HWP);
    int rem = px - bb * (3 * HWP);
    int yx  = rem % HWP;
    int y   = yx / WW;
    int xx  = yx - y * WW;
    u64 wv = splane[((size_t)bb * HH + y) * WORDS_X + (xx >> 6)];
    uint32_t bits = (uint32_t)((wv >> (xx & 63)) & 0xFFFFull);
    float4* o4 = (float4*)(out + (size_t)i * 16);
#pragma unroll
    for (int q = 0; q < 4; ++q) {
        float4 fv;
        fv.x = (bits >> (q * 4 + 0)) & 1 ? 1.0f : 0.0f;
        fv.y = (bits >> (q * 4 + 1)) & 1 ? 1.0f : 0.0f;
        fv.z = (bits >> (q * 4 + 2)) & 1 ? 1.0f : 0.0f;
        fv.w = (bits >> (q * 4 + 3)) & 1 ? 1.0f : 0.0f;
        o4[q] = fv;
    }
}

// ---------------------------------------------------------------------------
// Kernel 3b (coop fallback — planes in d_out tail): capture, sync, write
// ---------------------------------------------------------------------------
__global__ __launch_bounds__(256, 4)
void k_out_capture(const u64* __restrict__ splane, float* __restrict__ out)
{
    cg::grid_group grid = cg::this_grid();
    const int gtid = blockIdx.x * 256 + threadIdx.x;
    uint32_t vals[OSLOT];
#pragma unroll
    for (int n = 0; n < OSLOT; ++n) {
        int i = gtid + n * KNT;
        if (i < N16) {
            int px  = i * 16;
            int bb  = px / (3 * HWP);
            int rem = px - bb * (3 * HWP);
            int yx  = rem % HWP;
            int y   = yx / WW;
            int xx  = yx - y * WW;
            u64 wv = splane[((size_t)bb * HH + y) * WORDS_X + (xx >> 6)];
            vals[n] = (uint32_t)((wv >> (xx & 63)) & 0xFFFFull);
        }
    }
    grid.sync();
#pragma unroll
    for (int n = 0; n < OSLOT; ++n) {
        int i = gtid + n * KNT;
        if (i < N16) {
            uint32_t bits = vals[n];
            float4* o4 = (float4*)(out + (size_t)i * 16);
#pragma unroll
            for (int q = 0; q < 4; ++q) {
                float4 fv;
                fv.x = (bits >> (q * 4 + 0)) & 1 ? 1.0f : 0.0f;
                fv.y = (bits >> (q * 4 + 1)) & 1 ? 1.0f : 0.0f;
                fv.z = (bits >> (q * 4 + 2)) & 1 ? 1.0f : 0.0f;
                fv.w = (bits >> (q * 4 + 3)) & 1 ? 1.0f : 0.0f;
                o4[q] = fv;
            }
        }
    }
}

// ---------------------------------------------------------------------------
extern "C" void kernel_launch(void* const* d_in, const int* in_sizes, int n_in,
                              void* d_out, int out_size, void* d_ws, size_t ws_size,
                              hipStream_t stream)
{
    const float* x = (const float*)d_in[0];
    float* out = (float*)d_out;

    const bool use_ws = (d_ws != nullptr) && (ws_size >= 2 * PLANE_B);
    u64 *splane, *wplane;
    if (use_ws) {
        splane = (u64*)d_ws;
        wplane = (u64*)((char*)d_ws + PLANE_B);
    } else {
        char* tail = (char*)d_out + OUT_BYTES;
        wplane = (u64*)(tail - PLANE_B);
        splane = (u64*)(tail - 2 * PLANE_B);
    }

    k_gradnms<<<20 * 45 * BB, 256, 0, stream>>>(x, splane, wplane);
    k_hyst_local<<<BB, 768, 0, stream>>>(splane, wplane);

    if (use_ws) {
        k_out<<<N16 / 256, 256, 0, stream>>>(splane, out);
    } else {
        void* args[] = { (void*)&splane, (void*)&out };
        hipLaunchCooperativeKernel((void*)k_out_capture, dim3(KGRID), dim3(256),
                                   args, 0, stream);
    }
}